// Round 7
// baseline (467.554 us; speedup 1.0000x reference)
//
#include <hip/hip_runtime.h>

// ---------------- constants ----------------
#define BB   512   // batch
#define SS   256   // seq len
#define EE   128   // emb dim
#define HH   128   // per-dir hidden
#define LL   59    // labels
#define STARTL 57
#define STOPL  58
#define VOCAB 50000

typedef float  f32x4  __attribute__((ext_vector_type(4)));
typedef short  bf16x8 __attribute__((ext_vector_type(8)));
typedef short  s16x4  __attribute__((ext_vector_type(4)));

__device__ __forceinline__ short f2bf(float f) {
    unsigned u = __float_as_uint(f);
    u += 0x7FFFu + ((u >> 16) & 1u);   // RNE
    return (short)(u >> 16);
}
__device__ __forceinline__ float bf2f(unsigned short s) {
    return __uint_as_float(((unsigned)s) << 16);
}
__device__ __forceinline__ float sigf(float x) {
    float e = __builtin_amdgcn_exp2f(-1.44269504f * x);
    return __builtin_amdgcn_rcpf(1.0f + e);
}
__device__ __forceinline__ float tanhf_(float x) {
    float e = __builtin_amdgcn_exp2f(2.88539008f * x);
    return 1.0f - 2.0f * __builtin_amdgcn_rcpf(e + 1.0f);
}
__device__ __forceinline__ float wmax64(float v) {
    #pragma unroll
    for (int o = 32; o; o >>= 1) v = fmaxf(v, __shfl_xor(v, o));
    return v;
}
__device__ __forceinline__ float wsum64(float v) {
    #pragma unroll
    for (int o = 32; o; o >>= 1) v += __shfl_xor(v, o);
    return v;
}
// LDS-only barrier: global ops stay in flight across it.
__device__ __forceinline__ void bar_lds() {
    asm volatile("s_waitcnt lgkmcnt(0)\n\ts_barrier" ::: "memory");
}

// ---------------- kernel 0: f32 -> bf16 tables + bias sums ----------------
__global__ __launch_bounds__(256) void conv_k(
    const float* __restrict__ embed,
    const float* __restrict__ Wih_f, const float* __restrict__ Wih_b,
    const float* __restrict__ Whh_f, const float* __restrict__ Whh_b,
    const float* __restrict__ bih_f, const float* __restrict__ bhh_f,
    const float* __restrict__ bih_b, const float* __restrict__ bhh_b,
    unsigned short* __restrict__ ebf, unsigned short* __restrict__ wix,
    unsigned short* __restrict__ whb, float* __restrict__ bsum)
{
    const int W1 = VOCAB * EE / 4;      // embed float4
    const int W2 = W1 + 2 * 16384;      // wix  (Wih both dirs)
    const int W3 = W2 + 2 * 16384;      // whb  (Whh both dirs)
    const int W4 = W3 + 1024;           // bias sums
    for (int i = blockIdx.x * blockDim.x + threadIdx.x; i < W4;
         i += gridDim.x * blockDim.x) {
        if (i < W1) {
            float4 v = ((const float4*)embed)[i];
            s16x4 s = { f2bf(v.x), f2bf(v.y), f2bf(v.z), f2bf(v.w) };
            ((s16x4*)ebf)[i] = s;
        } else if (i < W2) {
            const int j = i - W1, d = j >> 14, e = j & 16383;
            float4 v = ((const float4*)(d ? Wih_b : Wih_f))[e];
            s16x4 s = { f2bf(v.x), f2bf(v.y), f2bf(v.z), f2bf(v.w) };
            ((s16x4*)wix)[d * 16384 + e] = s;
        } else if (i < W3) {
            const int j = i - W2, d = j >> 14, e = j & 16383;
            float4 v = ((const float4*)(d ? Whh_b : Whh_f))[e];
            s16x4 s = { f2bf(v.x), f2bf(v.y), f2bf(v.z), f2bf(v.w) };
            ((s16x4*)whb)[d * 16384 + e] = s;
        } else {
            const int m = i - W3, d = m >> 9, c = m & 511;
            bsum[d * 512 + c] = d ? (bih_b[c] + bhh_b[c]) : (bih_f[c] + bhh_f[c]);
        }
    }
}

// ---------------- kernel 1: fused BiLSTM (wave-specialized) ----------------
// 256 blocks (128 row-tiles x 2 dirs), 16 waves (1024 thr), 1 block/CU.
// Waves 0-7:  h-recurrence for slot w (fh 64 + wb 16 VGPRs), dilated 4-row
//             tile (real rows {0,4,8,12}) -> 10 transcendentals/lane/step.
// Waves 8-15: x-producer for slot w-8 (fx 64 VGPRs): gather emb(x[t+1]),
//             16 MFMA, +bias, pack bf16 -> LDS gxb[nxt]. Off the h critical
//             path; the gx HBM round-trip (536 MB) is eliminated.
// lgkm-only barrier per step; fp stores + ebf gathers stay in flight.
__global__ __launch_bounds__(1024, 4) void lstm_f(
    const int* __restrict__ x, const unsigned short* __restrict__ ebf,
    const unsigned short* __restrict__ wix, const unsigned short* __restrict__ whb,
    const float* __restrict__ bsum,
    const float* __restrict__ h0, const float* __restrict__ c0,
    const float* __restrict__ Wout,
    unsigned short* __restrict__ fpF, unsigned short* __restrict__ fpB)
{
    const int tid = threadIdx.x;
    const int w = tid >> 6, l = tid & 63, qd = l >> 4, n = l & 15;
    const int rt = blockIdx.x & 127, dir = blockIdx.x >> 7;
    const int b0 = rt * 4;
    unsigned short* fp = dir ? fpB : fpF;

    __shared__ short hbuf[2][2048];   // [octet][tile-row 0..15][8]; pads stay 0
    __shared__ short gxb[2][2048];    // [slot w][qd][n][gate 0..3] bf16
    __shared__ int   xsh[4 * 256];    // [j 0..3][t]

    // zero both hbuf buffers (1024 thr x 4 shorts = 8192 shorts) + stage x
    ((s16x4*)hbuf)[tid] = (s16x4)0;
    xsh[tid] = x[(size_t)(b0 + (tid >> 8)) * SS + (tid & 255)];

    if (w < 8) {
        // ---------- h-wave ----------
        bf16x8 fh[4][4];
        #pragma unroll
        for (int g = 0; g < 4; ++g) {
            const int row = g * 128 + 16 * w + n;
            #pragma unroll
            for (int kk = 0; kk < 4; ++kk)
                fh[g][kk] = *(const bf16x8*)(whb + dir * 65536 + (size_t)row * 128 + kk * 32 + qd * 8);
        }
        bf16x8 wb[4];
        {
            const int col = (w & 3) * 16 + n;
            #pragma unroll
            for (int kk = 0; kk < 4; ++kk) {
                bf16x8 v = (bf16x8)0;
                if (w >= 4 && col < LL) {
                    const float* p = Wout + (size_t)col * 256 + dir * 128 + kk * 32 + qd * 8;
                    #pragma unroll
                    for (int j = 0; j < 8; ++j) v[j] = f2bf(p[j]);
                }
                wb[kk] = v;
            }
        }
        float cst = c0[((size_t)dir * BB + b0 + qd) * HH + 16 * w + n];

        __syncthreads();   // B1: zeros + xsh visible
        {   // h0 -> hbuf[0] tile-rows {0,4,8,12}  (tid < 512 covers 4x128)
            const int j = tid >> 7, c = tid & 127;
            hbuf[0][((c >> 3) * 16 + 4 * j) * 8 + (c & 7)] =
                f2bf(h0[((size_t)dir * BB + b0 + j) * HH + c]);
        }
        __syncthreads();   // B2: hbuf[0] + gxb[0] ready

        const int hid = 16 * w + n, hc = hid >> 3, ho = hid & 7;
        const int gslot = (w * 64 + qd * 16 + n) * 4;

        for (int ts = 0; ts < SS; ++ts) {
            const int cur = ts & 1, nxt = cur ^ 1;

            const int2 gi = *(const int2*)&gxb[cur][gslot];

            bf16x8 ah[4];
            #pragma unroll
            for (int kk = 0; kk < 4; ++kk)
                ah[kk] = *(const bf16x8*)&hbuf[cur][((kk * 4 + qd) * 16 + n) * 8];

            f32x4 acc[4] = { {0,0,0,0}, {0,0,0,0}, {0,0,0,0}, {0,0,0,0} };
            acc[0][0] = __uint_as_float((unsigned)gi.x << 16);
            acc[1][0] = __uint_as_float((unsigned)gi.x & 0xFFFF0000u);
            acc[2][0] = __uint_as_float((unsigned)gi.y << 16);
            acc[3][0] = __uint_as_float((unsigned)gi.y & 0xFFFF0000u);

            #pragma unroll
            for (int kk = 0; kk < 4; ++kk) {
                #pragma unroll
                for (int g = 0; g < 4; ++g)
                    acc[g] = __builtin_amdgcn_mfma_f32_16x16x32_bf16(ah[kk], fh[g][kk], acc[g], 0, 0, 0);
            }

            if (w >= 4 && ts > 0) {   // project h_{ts-1} (reuses ah)
                f32x4 pa = {0, 0, 0, 0};
                #pragma unroll
                for (int kk = 0; kk < 4; ++kk)
                    pa = __builtin_amdgcn_mfma_f32_16x16x32_bf16(ah[kk], wb[kk], pa, 0, 0, 0);
                const int tep = dir ? (SS - ts) : (ts - 1);
                fp[((size_t)(b0 + qd) * SS + tep) * 64 + (w & 3) * 16 + n]
                    = (unsigned short)f2bf(pa[0]);
            }

            {   // gates: only r=0 real
                const float iv = sigf(acc[0][0]);
                const float fv = sigf(acc[1][0]);
                const float gv = tanhf_(acc[2][0]);
                const float ov = sigf(acc[3][0]);
                const float cc = fv * cst + iv * gv;
                cst = cc;
                hbuf[nxt][(hc * 16 + 4 * qd) * 8 + ho] = f2bf(ov * tanhf_(cc));
            }
            bar_lds();
        }

        if (w >= 4) {   // project h_{SS-1} (in hbuf[0], SS even)
            f32x4 pa = {0, 0, 0, 0};
            #pragma unroll
            for (int kk = 0; kk < 4; ++kk) {
                const bf16x8 a = *(const bf16x8*)&hbuf[0][((kk * 4 + qd) * 16 + n) * 8];
                pa = __builtin_amdgcn_mfma_f32_16x16x32_bf16(a, wb[kk], pa, 0, 0, 0);
            }
            const int tep = dir ? 0 : (SS - 1);
            fp[((size_t)(b0 + qd) * SS + tep) * 64 + (w & 3) * 16 + n]
                = (unsigned short)f2bf(pa[0]);
        }
    } else {
        // ---------- x-wave (slot ws = w-8) ----------
        const int ws = w - 8;
        bf16x8 fx[4][4]; float bs[4];
        #pragma unroll
        for (int g = 0; g < 4; ++g) {
            const int col = g * 128 + 16 * ws + n;
            bs[g] = bsum[dir * 512 + col];
            #pragma unroll
            for (int kk = 0; kk < 4; ++kk)
                fx[g][kk] = *(const bf16x8*)(wix + dir * 65536 + (size_t)col * 128 + kk * 32 + qd * 8);
        }
        const int gslot = (ws * 64 + qd * 16 + n) * 4;
        const int jrow = (n >> 2) * 256;   // A row m=n -> batch j = n>>2

        __syncthreads();   // B1
        {   // gx(0) -> gxb[0]
            const int te = dir ? (SS - 1) : 0;
            const int xi = xsh[jrow + te];
            const unsigned short* er = ebf + (size_t)xi * EE + qd * 8;
            bf16x8 a0 = *(const bf16x8*)(er);
            bf16x8 a1 = *(const bf16x8*)(er + 32);
            bf16x8 a2 = *(const bf16x8*)(er + 64);
            bf16x8 a3 = *(const bf16x8*)(er + 96);
            f32x4 ac[4] = { {0,0,0,0}, {0,0,0,0}, {0,0,0,0}, {0,0,0,0} };
            #pragma unroll
            for (int g = 0; g < 4; ++g) {
                ac[g] = __builtin_amdgcn_mfma_f32_16x16x32_bf16(a0, fx[g][0], ac[g], 0, 0, 0);
                ac[g] = __builtin_amdgcn_mfma_f32_16x16x32_bf16(a1, fx[g][1], ac[g], 0, 0, 0);
                ac[g] = __builtin_amdgcn_mfma_f32_16x16x32_bf16(a2, fx[g][2], ac[g], 0, 0, 0);
                ac[g] = __builtin_amdgcn_mfma_f32_16x16x32_bf16(a3, fx[g][3], ac[g], 0, 0, 0);
            }
            s16x4 pk = { f2bf(ac[0][0] + bs[0]), f2bf(ac[1][0] + bs[1]),
                         f2bf(ac[2][0] + bs[2]), f2bf(ac[3][0] + bs[3]) };
            *(s16x4*)&gxb[0][gslot] = pk;
        }
        __syncthreads();   // B2

        for (int ts = 0; ts < SS; ++ts) {
            const int nxt = (ts & 1) ^ 1;
            if (ts + 1 < SS) {
                const int te = dir ? (SS - 2 - ts) : (ts + 1);
                const int xi = xsh[jrow + te];
                const unsigned short* er = ebf + (size_t)xi * EE + qd * 8;
                bf16x8 a0 = *(const bf16x8*)(er);
                bf16x8 a1 = *(const bf16x8*)(er + 32);
                bf16x8 a2 = *(const bf16x8*)(er + 64);
                bf16x8 a3 = *(const bf16x8*)(er + 96);
                f32x4 ac[4] = { {0,0,0,0}, {0,0,0,0}, {0,0,0,0}, {0,0,0,0} };
                #pragma unroll
                for (int g = 0; g < 4; ++g) {
                    ac[g] = __builtin_amdgcn_mfma_f32_16x16x32_bf16(a0, fx[g][0], ac[g], 0, 0, 0);
                    ac[g] = __builtin_amdgcn_mfma_f32_16x16x32_bf16(a1, fx[g][1], ac[g], 0, 0, 0);
                    ac[g] = __builtin_amdgcn_mfma_f32_16x16x32_bf16(a2, fx[g][2], ac[g], 0, 0, 0);
                    ac[g] = __builtin_amdgcn_mfma_f32_16x16x32_bf16(a3, fx[g][3], ac[g], 0, 0, 0);
                }
                s16x4 pk = { f2bf(ac[0][0] + bs[0]), f2bf(ac[1][0] + bs[1]),
                             f2bf(ac[2][0] + bs[2]), f2bf(ac[3][0] + bs[3]) };
                *(s16x4*)&gxb[nxt][gslot] = pk;
            }
            bar_lds();
        }
    }
}

// ---------------- kernel 2: CRF forward + gold + reduce ----------------
// One wave per batch element, 512 blocks x 64 thr (all 256 CUs, 2 waves/CU).
// launch_bounds(64,1) lifts the VGPR cap so etr[59] stays register-resident
// (R6 showed VGPR_Count=60 -> the whole exp(trans) table was spilling).
__global__ __launch_bounds__(64, 1) void crf_k(
    const unsigned short* __restrict__ fpF, const unsigned short* __restrict__ fpB,
    const float* __restrict__ bout, const int* __restrict__ y,
    const float* __restrict__ trans, float* __restrict__ out)
{
    const int j = threadIdx.x;
    const int b = blockIdx.x;
    const size_t bS = (size_t)b * SS;
    const bool valid = (j < LL);
    const int  jr = valid ? j : (LL - 1);

    float etr[LL];
    #pragma unroll
    for (int i = 0; i < LL; ++i) {
        const float t = trans[jr * LL + i];
        etr[i] = valid ? __builtin_amdgcn_exp2f(t * 1.44269504f) : 0.0f;
    }
    const float bo = valid ? bout[jr] : 0.0f;

    float alpha = valid ? ((j == STARTL) ? 0.0f : -10000.0f) : -1e30f;

    float fF[8], fB[8];
    #pragma unroll
    for (int q = 0; q < 8; ++q) {
        fF[q] = bf2f(fpF[(bS + q) * 64 + j]);
        fB[q] = bf2f(fpB[(bS + q) * 64 + j]);
    }

    for (int t0 = 0; t0 < SS; t0 += 8) {
        float nF[8], nB[8];
        #pragma unroll
        for (int q = 0; q < 8; ++q) { nF[q] = 0.0f; nB[q] = 0.0f; }
        if (t0 + 8 < SS) {
            #pragma unroll
            for (int q = 0; q < 8; ++q) {
                nF[q] = bf2f(fpF[(bS + t0 + 8 + q) * 64 + j]);
                nB[q] = bf2f(fpB[(bS + t0 + 8 + q) * 64 + j]);
            }
        }
        #pragma unroll
        for (int u = 0; u < 8; ++u) {
            const float K = fmaxf(
                __uint_as_float(__builtin_amdgcn_readlane(__float_as_uint(alpha), 1)),
                __uint_as_float(__builtin_amdgcn_readlane(__float_as_uint(alpha), STARTL)));
            const float ea = __builtin_amdgcn_exp2f((alpha - K) * 1.44269504f);
            float d0 = 0.0f, d1 = 0.0f, d2 = 0.0f, d3 = 0.0f;
            #pragma unroll
            for (int i = 0; i < LL; i += 4) {
                d0 += etr[i] * __uint_as_float(__builtin_amdgcn_readlane(__float_as_uint(ea), i));
                if (i + 1 < LL) d1 += etr[i+1] * __uint_as_float(__builtin_amdgcn_readlane(__float_as_uint(ea), i+1));
                if (i + 2 < LL) d2 += etr[i+2] * __uint_as_float(__builtin_amdgcn_readlane(__float_as_uint(ea), i+2));
                if (i + 3 < LL) d3 += etr[i+3] * __uint_as_float(__builtin_amdgcn_readlane(__float_as_uint(ea), i+3));
            }
            const float dot = (d0 + d1) + (d2 + d3);
            alpha = (fF[u] + fB[u] + bo) + K + 0.69314718f * __builtin_amdgcn_logf(dot);
        }
        #pragma unroll
        for (int q = 0; q < 8; ++q) { fF[q] = nF[q]; fB[q] = nB[q]; }
    }

    const float v  = alpha + trans[STOPL * LL + jr];
    const float m2 = wmax64(v);
    const float s  = wsum64(__builtin_amdgcn_exp2f((v - m2) * 1.44269504f));
    const float fwd = m2 + 0.69314718f * __builtin_amdgcn_logf(s);

    float g = 0.0f;
    #pragma unroll
    for (int q = 0; q < 4; ++q) {
        const int t  = q * 64 + j;
        const int yt = y[bS + t];
        const int yp = t ? y[bS + t - 1] : STARTL;
        g += bf2f(fpF[(bS + t) * 64 + yt]) + bf2f(fpB[(bS + t) * 64 + yt])
           + bout[yt] + trans[yt * LL + yp];
    }
    g = wsum64(g);

    if (j == 0) {
        g += trans[STOPL * LL + y[bS + SS - 1]];
        atomicAdd(out, fwd - g);
    }
}

// ---------------- launcher ----------------
extern "C" void kernel_launch(void* const* d_in, const int* in_sizes, int n_in,
                              void* d_out, int out_size, void* d_ws, size_t ws_size,
                              hipStream_t stream)
{
    (void)in_sizes; (void)n_in; (void)out_size; (void)ws_size;
    const int*   x      = (const int*)  d_in[0];
    const int*   y      = (const int*)  d_in[1];
    const float* embed  = (const float*)d_in[2];
    const float* Wih_f  = (const float*)d_in[3];
    const float* Whh_f  = (const float*)d_in[4];
    const float* bih_f  = (const float*)d_in[5];
    const float* bhh_f  = (const float*)d_in[6];
    const float* Wih_b  = (const float*)d_in[7];
    const float* Whh_b  = (const float*)d_in[8];
    const float* bih_b  = (const float*)d_in[9];
    const float* bhh_b  = (const float*)d_in[10];
    const float* Wout   = (const float*)d_in[11];
    const float* bout   = (const float*)d_in[12];
    const float* trans  = (const float*)d_in[13];
    const float* h0     = (const float*)d_in[14];
    const float* c0     = (const float*)d_in[15];

    const size_t MiB = 1ull << 20;
    unsigned short* fpF  = (unsigned short*)d_ws;                                   // 16 MiB
    unsigned short* fpB  = (unsigned short*)((char*)d_ws + 16 * MiB);               // 16 MiB
    unsigned short* ebf  = (unsigned short*)((char*)d_ws + 32 * MiB);               // 12.8 MB
    unsigned short* wix  = (unsigned short*)((char*)d_ws + 45 * MiB);               // 256 KiB
    unsigned short* whb  = (unsigned short*)((char*)d_ws + 45 * MiB + 256 * 1024);  // 256 KiB
    float*          bsum = (float*)((char*)d_ws + 45 * MiB + 512 * 1024);           // 4 KiB

    hipMemsetAsync(d_out, 0, sizeof(float), stream);
    conv_k<<<2048, 256, 0, stream>>>(embed, Wih_f, Wih_b, Whh_f, Whh_b,
                                     bih_f, bhh_f, bih_b, bhh_b,
                                     ebf, wix, whb, bsum);
    lstm_f<<<256, 1024, 0, stream>>>(x, ebf, wix, whb, bsum, h0, c0, Wout,
                                     fpF, fpB);
    crf_k<<<BB, 64, 0, stream>>>(fpF, fpB, bout, y, trans, (float*)d_out);
}

// Round 8
// 432.271 us; speedup vs baseline: 1.0816x; 1.0816x over previous
//
#include <hip/hip_runtime.h>

// ---------------- constants ----------------
#define BB   512   // batch
#define SS   256   // seq len
#define EE   128   // emb dim
#define HH   128   // per-dir hidden
#define LL   59    // labels
#define STARTL 57
#define STOPL  58
#define VOCAB 50000

typedef float  f32x4  __attribute__((ext_vector_type(4)));
typedef short  bf16x8 __attribute__((ext_vector_type(8)));
typedef short  s16x4  __attribute__((ext_vector_type(4)));

__device__ __forceinline__ short f2bf(float f) {
    unsigned u = __float_as_uint(f);
    u += 0x7FFFu + ((u >> 16) & 1u);   // RNE
    return (short)(u >> 16);
}
__device__ __forceinline__ float bf2f(unsigned short s) {
    return __uint_as_float(((unsigned)s) << 16);
}
__device__ __forceinline__ float sigf(float x) {
    float e = __builtin_amdgcn_exp2f(-1.44269504f * x);
    return __builtin_amdgcn_rcpf(1.0f + e);
}
__device__ __forceinline__ float tanhf_(float x) {
    float e = __builtin_amdgcn_exp2f(2.88539008f * x);
    return 1.0f - 2.0f * __builtin_amdgcn_rcpf(e + 1.0f);
}
__device__ __forceinline__ float wmax64(float v) {
    #pragma unroll
    for (int o = 32; o; o >>= 1) v = fmaxf(v, __shfl_xor(v, o));
    return v;
}
__device__ __forceinline__ float wsum64(float v) {
    #pragma unroll
    for (int o = 32; o; o >>= 1) v += __shfl_xor(v, o);
    return v;
}
// LDS-only barrier: global ops stay in flight across it.
__device__ __forceinline__ void bar_lds() {
    asm volatile("s_waitcnt lgkmcnt(0)\n\ts_barrier" ::: "memory");
}

// ---------------- kernel 0: f32 -> bf16 tables + bias sums ----------------
__global__ __launch_bounds__(256) void conv_k(
    const float* __restrict__ embed,
    const float* __restrict__ Wih_f, const float* __restrict__ Wih_b,
    const float* __restrict__ Whh_f, const float* __restrict__ Whh_b,
    const float* __restrict__ bih_f, const float* __restrict__ bhh_f,
    const float* __restrict__ bih_b, const float* __restrict__ bhh_b,
    unsigned short* __restrict__ ebf, unsigned short* __restrict__ wix,
    unsigned short* __restrict__ whb, float* __restrict__ bsum)
{
    const int W1 = VOCAB * EE / 4;      // embed float4
    const int W2 = W1 + 2 * 16384;      // wix  (Wih both dirs)
    const int W3 = W2 + 2 * 16384;      // whb  (Whh both dirs)
    const int W4 = W3 + 1024;           // bias sums
    for (int i = blockIdx.x * blockDim.x + threadIdx.x; i < W4;
         i += gridDim.x * blockDim.x) {
        if (i < W1) {
            float4 v = ((const float4*)embed)[i];
            s16x4 s = { f2bf(v.x), f2bf(v.y), f2bf(v.z), f2bf(v.w) };
            ((s16x4*)ebf)[i] = s;
        } else if (i < W2) {
            const int j = i - W1, d = j >> 14, e = j & 16383;
            float4 v = ((const float4*)(d ? Wih_b : Wih_f))[e];
            s16x4 s = { f2bf(v.x), f2bf(v.y), f2bf(v.z), f2bf(v.w) };
            ((s16x4*)wix)[d * 16384 + e] = s;
        } else if (i < W3) {
            const int j = i - W2, d = j >> 14, e = j & 16383;
            float4 v = ((const float4*)(d ? Whh_b : Whh_f))[e];
            s16x4 s = { f2bf(v.x), f2bf(v.y), f2bf(v.z), f2bf(v.w) };
            ((s16x4*)whb)[d * 16384 + e] = s;
        } else {
            const int m = i - W3, d = m >> 9, c = m & 511;
            bsum[d * 512 + c] = d ? (bih_b[c] + bhh_b[c]) : (bih_f[c] + bhh_f[c]);
        }
    }
}

// ---------------- kernel 1: fused BiLSTM (wave-specialized, 2 slots/wave) ----------------
// 256 blocks (128 row-tiles x 2 dirs), 512 thr = 8 waves, launch_bounds(512,2)
// -> 256 VGPRs/wave: weight frags stay register-resident (R7's 1024-thr
// version capped waves at 128 VGPRs -> 24.8 GB of spill refetch per launch).
// Waves 0-3: h-recurrence, 2 col-slots each (fh 128 VGPR) + Wout col-tile w.
// Waves 4-7: x-producers, 2 col-slots each (fx 128 VGPR): emb(x[t+1])@Wih^T
//            + bias -> LDS gxb[nxt]. Both slots share one A-frag.
// Dilated 4-row tile (real rows {0,4,8,12}); lgkm-only barrier per step.
__global__ __launch_bounds__(512, 2) void lstm_f(
    const int* __restrict__ x, const unsigned short* __restrict__ ebf,
    const unsigned short* __restrict__ wix, const unsigned short* __restrict__ whb,
    const float* __restrict__ bsum,
    const float* __restrict__ h0, const float* __restrict__ c0,
    const float* __restrict__ Wout,
    unsigned short* __restrict__ fpF, unsigned short* __restrict__ fpB)
{
    const int tid = threadIdx.x;
    const int w = tid >> 6, l = tid & 63, qd = l >> 4, n = l & 15;
    const int rt = blockIdx.x & 127, dir = blockIdx.x >> 7;
    const int b0 = rt * 4;
    unsigned short* fp = dir ? fpB : fpF;

    __shared__ short hbuf[2][2048];   // [octet][tile-row 0..15][8]; pads stay 0
    __shared__ short gxb[2][2048];    // [slot 0..7][qd][n][gate 0..3] bf16
    __shared__ int   xsh[4 * 256];    // [j 0..3][t]

    // zero both hbuf buffers + stage x tile
    #pragma unroll
    for (int i = 0; i < 2; ++i) ((s16x4*)hbuf)[tid + i * 512] = (s16x4)0;
    #pragma unroll
    for (int i = 0; i < 2; ++i) {
        const int k = tid + i * 512;
        xsh[k] = x[(size_t)(b0 + (k >> 8)) * SS + (k & 255)];
    }

    if (w < 4) {
        // ---------- h-wave: slots 2w, 2w+1 ----------
        const int s0 = 2 * w, s1 = 2 * w + 1;
        bf16x8 fh0[4][4], fh1[4][4];
        #pragma unroll
        for (int g = 0; g < 4; ++g) {
            #pragma unroll
            for (int kk = 0; kk < 4; ++kk) {
                fh0[g][kk] = *(const bf16x8*)(whb + dir * 65536
                             + (size_t)(g * 128 + 16 * s0 + n) * 128 + kk * 32 + qd * 8);
                fh1[g][kk] = *(const bf16x8*)(whb + dir * 65536
                             + (size_t)(g * 128 + 16 * s1 + n) * 128 + kk * 32 + qd * 8);
            }
        }
        bf16x8 wb[4];
        {
            const int col = w * 16 + n;     // col-tiles 0..3 cover 64 >= LL
            #pragma unroll
            for (int kk = 0; kk < 4; ++kk) {
                bf16x8 v = (bf16x8)0;
                if (col < LL) {
                    const float* p = Wout + (size_t)col * 256 + dir * 128 + kk * 32 + qd * 8;
                    #pragma unroll
                    for (int j = 0; j < 8; ++j) v[j] = f2bf(p[j]);
                }
                wb[kk] = v;
            }
        }
        float cst0 = c0[((size_t)dir * BB + b0 + qd) * HH + 16 * s0 + n];
        float cst1 = c0[((size_t)dir * BB + b0 + qd) * HH + 16 * s1 + n];

        __syncthreads();   // B1: zeros + xsh visible
        {   // h0 -> hbuf[0] tile-rows {0,4,8,12} (512 thr = 4 rows x 128 cols)
            const int j = tid >> 7, c = tid & 127;
            hbuf[0][((c >> 3) * 16 + 4 * j) * 8 + (c & 7)] =
                f2bf(h0[((size_t)dir * BB + b0 + j) * HH + c]);
        }
        __syncthreads();   // B2: hbuf[0] + gxb[0] ready

        const int hid0 = 16 * s0 + n, hc0 = hid0 >> 3, ho0 = hid0 & 7;
        const int hid1 = 16 * s1 + n, hc1 = hid1 >> 3, ho1 = hid1 & 7;
        const int gs0 = (s0 * 64 + qd * 16 + n) * 4;
        const int gs1 = (s1 * 64 + qd * 16 + n) * 4;

        for (int ts = 0; ts < SS; ++ts) {
            const int cur = ts & 1, nxt = cur ^ 1;

            const int2 gi0 = *(const int2*)&gxb[cur][gs0];
            const int2 gi1 = *(const int2*)&gxb[cur][gs1];

            bf16x8 ah[4];
            #pragma unroll
            for (int kk = 0; kk < 4; ++kk)
                ah[kk] = *(const bf16x8*)&hbuf[cur][((kk * 4 + qd) * 16 + n) * 8];

            f32x4 a0[4] = { {0,0,0,0}, {0,0,0,0}, {0,0,0,0}, {0,0,0,0} };
            f32x4 a1[4] = { {0,0,0,0}, {0,0,0,0}, {0,0,0,0}, {0,0,0,0} };
            a0[0][0] = __uint_as_float((unsigned)gi0.x << 16);
            a0[1][0] = __uint_as_float((unsigned)gi0.x & 0xFFFF0000u);
            a0[2][0] = __uint_as_float((unsigned)gi0.y << 16);
            a0[3][0] = __uint_as_float((unsigned)gi0.y & 0xFFFF0000u);
            a1[0][0] = __uint_as_float((unsigned)gi1.x << 16);
            a1[1][0] = __uint_as_float((unsigned)gi1.x & 0xFFFF0000u);
            a1[2][0] = __uint_as_float((unsigned)gi1.y << 16);
            a1[3][0] = __uint_as_float((unsigned)gi1.y & 0xFFFF0000u);

            #pragma unroll
            for (int kk = 0; kk < 4; ++kk) {
                #pragma unroll
                for (int g = 0; g < 4; ++g) {
                    a0[g] = __builtin_amdgcn_mfma_f32_16x16x32_bf16(ah[kk], fh0[g][kk], a0[g], 0, 0, 0);
                    a1[g] = __builtin_amdgcn_mfma_f32_16x16x32_bf16(ah[kk], fh1[g][kk], a1[g], 0, 0, 0);
                }
            }

            if (ts > 0) {   // project h_{ts-1} (reuses ah)
                f32x4 pa = {0, 0, 0, 0};
                #pragma unroll
                for (int kk = 0; kk < 4; ++kk)
                    pa = __builtin_amdgcn_mfma_f32_16x16x32_bf16(ah[kk], wb[kk], pa, 0, 0, 0);
                const int tep = dir ? (SS - ts) : (ts - 1);
                fp[((size_t)(b0 + qd) * SS + tep) * 64 + w * 16 + n]
                    = (unsigned short)f2bf(pa[0]);
            }

            {   // gates (r=0 real), both slots
                const float iv0 = sigf(a0[0][0]), fv0 = sigf(a0[1][0]);
                const float gv0 = tanhf_(a0[2][0]), ov0 = sigf(a0[3][0]);
                const float cc0 = fv0 * cst0 + iv0 * gv0;
                cst0 = cc0;
                hbuf[nxt][(hc0 * 16 + 4 * qd) * 8 + ho0] = f2bf(ov0 * tanhf_(cc0));
                const float iv1 = sigf(a1[0][0]), fv1 = sigf(a1[1][0]);
                const float gv1 = tanhf_(a1[2][0]), ov1 = sigf(a1[3][0]);
                const float cc1 = fv1 * cst1 + iv1 * gv1;
                cst1 = cc1;
                hbuf[nxt][(hc1 * 16 + 4 * qd) * 8 + ho1] = f2bf(ov1 * tanhf_(cc1));
            }
            bar_lds();
        }

        {   // project h_{SS-1} (in hbuf[0], SS even)
            f32x4 pa = {0, 0, 0, 0};
            #pragma unroll
            for (int kk = 0; kk < 4; ++kk) {
                const bf16x8 a = *(const bf16x8*)&hbuf[0][((kk * 4 + qd) * 16 + n) * 8];
                pa = __builtin_amdgcn_mfma_f32_16x16x32_bf16(a, wb[kk], pa, 0, 0, 0);
            }
            const int tep = dir ? 0 : (SS - 1);
            fp[((size_t)(b0 + qd) * SS + tep) * 64 + w * 16 + n]
                = (unsigned short)f2bf(pa[0]);
        }
    } else {
        // ---------- x-wave: slots 2(w-4), 2(w-4)+1 ----------
        const int s0 = 2 * (w - 4), s1 = s0 + 1;
        bf16x8 fx0[4][4], fx1[4][4]; float bs0[4], bs1[4];
        #pragma unroll
        for (int g = 0; g < 4; ++g) {
            bs0[g] = bsum[dir * 512 + g * 128 + 16 * s0 + n];
            bs1[g] = bsum[dir * 512 + g * 128 + 16 * s1 + n];
            #pragma unroll
            for (int kk = 0; kk < 4; ++kk) {
                fx0[g][kk] = *(const bf16x8*)(wix + dir * 65536
                             + (size_t)(g * 128 + 16 * s0 + n) * 128 + kk * 32 + qd * 8);
                fx1[g][kk] = *(const bf16x8*)(wix + dir * 65536
                             + (size_t)(g * 128 + 16 * s1 + n) * 128 + kk * 32 + qd * 8);
            }
        }
        const int gs0 = (s0 * 64 + qd * 16 + n) * 4;
        const int gs1 = (s1 * 64 + qd * 16 + n) * 4;
        const int jrow = (n >> 2) * 256;   // A row n -> batch j = n>>2

        __syncthreads();   // B1

        auto produce = [&](int te, int buf) {
            const int xi = xsh[jrow + te];
            const unsigned short* er = ebf + (size_t)xi * EE + qd * 8;
            bf16x8 e0 = *(const bf16x8*)(er);
            bf16x8 e1 = *(const bf16x8*)(er + 32);
            bf16x8 e2 = *(const bf16x8*)(er + 64);
            bf16x8 e3 = *(const bf16x8*)(er + 96);
            f32x4 c0a[4] = { {0,0,0,0}, {0,0,0,0}, {0,0,0,0}, {0,0,0,0} };
            f32x4 c1a[4] = { {0,0,0,0}, {0,0,0,0}, {0,0,0,0}, {0,0,0,0} };
            #pragma unroll
            for (int g = 0; g < 4; ++g) {
                c0a[g] = __builtin_amdgcn_mfma_f32_16x16x32_bf16(e0, fx0[g][0], c0a[g], 0, 0, 0);
                c0a[g] = __builtin_amdgcn_mfma_f32_16x16x32_bf16(e1, fx0[g][1], c0a[g], 0, 0, 0);
                c0a[g] = __builtin_amdgcn_mfma_f32_16x16x32_bf16(e2, fx0[g][2], c0a[g], 0, 0, 0);
                c0a[g] = __builtin_amdgcn_mfma_f32_16x16x32_bf16(e3, fx0[g][3], c0a[g], 0, 0, 0);
                c1a[g] = __builtin_amdgcn_mfma_f32_16x16x32_bf16(e0, fx1[g][0], c1a[g], 0, 0, 0);
                c1a[g] = __builtin_amdgcn_mfma_f32_16x16x32_bf16(e1, fx1[g][1], c1a[g], 0, 0, 0);
                c1a[g] = __builtin_amdgcn_mfma_f32_16x16x32_bf16(e2, fx1[g][2], c1a[g], 0, 0, 0);
                c1a[g] = __builtin_amdgcn_mfma_f32_16x16x32_bf16(e3, fx1[g][3], c1a[g], 0, 0, 0);
            }
            s16x4 p0 = { f2bf(c0a[0][0] + bs0[0]), f2bf(c0a[1][0] + bs0[1]),
                         f2bf(c0a[2][0] + bs0[2]), f2bf(c0a[3][0] + bs0[3]) };
            s16x4 p1 = { f2bf(c1a[0][0] + bs1[0]), f2bf(c1a[1][0] + bs1[1]),
                         f2bf(c1a[2][0] + bs1[2]), f2bf(c1a[3][0] + bs1[3]) };
            *(s16x4*)&gxb[buf][gs0] = p0;
            *(s16x4*)&gxb[buf][gs1] = p1;
        };

        produce(dir ? SS - 1 : 0, 0);   // gx(0) -> gxb[0]
        __syncthreads();   // B2

        for (int ts = 0; ts < SS; ++ts) {
            const int nxt = (ts & 1) ^ 1;
            if (ts + 1 < SS)
                produce(dir ? (SS - 2 - ts) : (ts + 1), nxt);
            bar_lds();
        }
    }
}

// ---------------- kernel 2: CRF forward + gold + reduce ----------------
// One wave per batch element, 512 blocks x 64 thr; launch_bounds(64,1) lifts
// the VGPR cap so etr[59] stays register-resident.
__global__ __launch_bounds__(64, 1) void crf_k(
    const unsigned short* __restrict__ fpF, const unsigned short* __restrict__ fpB,
    const float* __restrict__ bout, const int* __restrict__ y,
    const float* __restrict__ trans, float* __restrict__ out)
{
    const int j = threadIdx.x;
    const int b = blockIdx.x;
    const size_t bS = (size_t)b * SS;
    const bool valid = (j < LL);
    const int  jr = valid ? j : (LL - 1);

    float etr[LL];
    #pragma unroll
    for (int i = 0; i < LL; ++i) {
        const float t = trans[jr * LL + i];
        etr[i] = valid ? __builtin_amdgcn_exp2f(t * 1.44269504f) : 0.0f;
    }
    const float bo = valid ? bout[jr] : 0.0f;

    float alpha = valid ? ((j == STARTL) ? 0.0f : -10000.0f) : -1e30f;

    float fF[8], fB[8];
    #pragma unroll
    for (int q = 0; q < 8; ++q) {
        fF[q] = bf2f(fpF[(bS + q) * 64 + j]);
        fB[q] = bf2f(fpB[(bS + q) * 64 + j]);
    }

    for (int t0 = 0; t0 < SS; t0 += 8) {
        float nF[8], nB[8];
        #pragma unroll
        for (int q = 0; q < 8; ++q) { nF[q] = 0.0f; nB[q] = 0.0f; }
        if (t0 + 8 < SS) {
            #pragma unroll
            for (int q = 0; q < 8; ++q) {
                nF[q] = bf2f(fpF[(bS + t0 + 8 + q) * 64 + j]);
                nB[q] = bf2f(fpB[(bS + t0 + 8 + q) * 64 + j]);
            }
        }
        #pragma unroll
        for (int u = 0; u < 8; ++u) {
            const float K = fmaxf(
                __uint_as_float(__builtin_amdgcn_readlane(__float_as_uint(alpha), 1)),
                __uint_as_float(__builtin_amdgcn_readlane(__float_as_uint(alpha), STARTL)));
            const float ea = __builtin_amdgcn_exp2f((alpha - K) * 1.44269504f);
            float d0 = 0.0f, d1 = 0.0f, d2 = 0.0f, d3 = 0.0f;
            #pragma unroll
            for (int i = 0; i < LL; i += 4) {
                d0 += etr[i] * __uint_as_float(__builtin_amdgcn_readlane(__float_as_uint(ea), i));
                if (i + 1 < LL) d1 += etr[i+1] * __uint_as_float(__builtin_amdgcn_readlane(__float_as_uint(ea), i+1));
                if (i + 2 < LL) d2 += etr[i+2] * __uint_as_float(__builtin_amdgcn_readlane(__float_as_uint(ea), i+2));
                if (i + 3 < LL) d3 += etr[i+3] * __uint_as_float(__builtin_amdgcn_readlane(__float_as_uint(ea), i+3));
            }
            const float dot = (d0 + d1) + (d2 + d3);
            alpha = (fF[u] + fB[u] + bo) + K + 0.69314718f * __builtin_amdgcn_logf(dot);
        }
        #pragma unroll
        for (int q = 0; q < 8; ++q) { fF[q] = nF[q]; fB[q] = nB[q]; }
    }

    const float v  = alpha + trans[STOPL * LL + jr];
    const float m2 = wmax64(v);
    const float s  = wsum64(__builtin_amdgcn_exp2f((v - m2) * 1.44269504f));
    const float fwd = m2 + 0.69314718f * __builtin_amdgcn_logf(s);

    float g = 0.0f;
    #pragma unroll
    for (int q = 0; q < 4; ++q) {
        const int t  = q * 64 + j;
        const int yt = y[bS + t];
        const int yp = t ? y[bS + t - 1] : STARTL;
        g += bf2f(fpF[(bS + t) * 64 + yt]) + bf2f(fpB[(bS + t) * 64 + yt])
           + bout[yt] + trans[yt * LL + yp];
    }
    g = wsum64(g);

    if (j == 0) {
        g += trans[STOPL * LL + y[bS + SS - 1]];
        atomicAdd(out, fwd - g);
    }
}

// ---------------- launcher ----------------
extern "C" void kernel_launch(void* const* d_in, const int* in_sizes, int n_in,
                              void* d_out, int out_size, void* d_ws, size_t ws_size,
                              hipStream_t stream)
{
    (void)in_sizes; (void)n_in; (void)out_size; (void)ws_size;
    const int*   x      = (const int*)  d_in[0];
    const int*   y      = (const int*)  d_in[1];
    const float* embed  = (const float*)d_in[2];
    const float* Wih_f  = (const float*)d_in[3];
    const float* Whh_f  = (const float*)d_in[4];
    const float* bih_f  = (const float*)d_in[5];
    const float* bhh_f  = (const float*)d_in[6];
    const float* Wih_b  = (const float*)d_in[7];
    const float* Whh_b  = (const float*)d_in[8];
    const float* bih_b  = (const float*)d_in[9];
    const float* bhh_b  = (const float*)d_in[10];
    const float* Wout   = (const float*)d_in[11];
    const float* bout   = (const float*)d_in[12];
    const float* trans  = (const float*)d_in[13];
    const float* h0     = (const float*)d_in[14];
    const float* c0     = (const float*)d_in[15];

    const size_t MiB = 1ull << 20;
    unsigned short* fpF  = (unsigned short*)d_ws;                                   // 16 MiB
    unsigned short* fpB  = (unsigned short*)((char*)d_ws + 16 * MiB);               // 16 MiB
    unsigned short* ebf  = (unsigned short*)((char*)d_ws + 32 * MiB);               // 12.8 MB
    unsigned short* wix  = (unsigned short*)((char*)d_ws + 45 * MiB);               // 256 KiB
    unsigned short* whb  = (unsigned short*)((char*)d_ws + 45 * MiB + 256 * 1024);  // 256 KiB
    float*          bsum = (float*)((char*)d_ws + 45 * MiB + 512 * 1024);           // 4 KiB

    hipMemsetAsync(d_out, 0, sizeof(float), stream);
    conv_k<<<2048, 256, 0, stream>>>(embed, Wih_f, Wih_b, Whh_f, Whh_b,
                                     bih_f, bhh_f, bih_b, bhh_b,
                                     ebf, wix, whb, bsum);
    lstm_f<<<256, 512, 0, stream>>>(x, ebf, wix, whb, bsum, h0, c0, Wout,
                                    fpF, fpB);
    crf_k<<<BB, 64, 0, stream>>>(fpF, fpB, bout, y, trans, (float*)d_out);
}

// Round 9
// 427.781 us; speedup vs baseline: 1.0930x; 1.0105x over previous
//
#include <hip/hip_runtime.h>

// ---------------- constants ----------------
#define BB   512   // batch
#define SS   256   // seq len
#define EE   128   // emb dim
#define HH   128   // per-dir hidden
#define LL   59    // labels
#define STARTL 57
#define STOPL  58
#define VOCAB 50000

typedef float  f32x4  __attribute__((ext_vector_type(4)));
typedef short  bf16x8 __attribute__((ext_vector_type(8)));
typedef short  s16x4  __attribute__((ext_vector_type(4)));

__device__ __forceinline__ short f2bf(float f) {
    unsigned u = __float_as_uint(f);
    u += 0x7FFFu + ((u >> 16) & 1u);   // RNE
    return (short)(u >> 16);
}
__device__ __forceinline__ float bf2f(unsigned short s) {
    return __uint_as_float(((unsigned)s) << 16);
}
__device__ __forceinline__ float sigf(float x) {
    float e = __builtin_amdgcn_exp2f(-1.44269504f * x);
    return __builtin_amdgcn_rcpf(1.0f + e);
}
__device__ __forceinline__ float tanhf_(float x) {
    float e = __builtin_amdgcn_exp2f(2.88539008f * x);
    return 1.0f - 2.0f * __builtin_amdgcn_rcpf(e + 1.0f);
}
__device__ __forceinline__ float wmax64(float v) {
    #pragma unroll
    for (int o = 32; o; o >>= 1) v = fmaxf(v, __shfl_xor(v, o));
    return v;
}
__device__ __forceinline__ float wsum64(float v) {
    #pragma unroll
    for (int o = 32; o; o >>= 1) v += __shfl_xor(v, o);
    return v;
}
// LDS-only barrier: global ops stay in flight across it.
__device__ __forceinline__ void bar_lds() {
    asm volatile("s_waitcnt lgkmcnt(0)\n\ts_barrier" ::: "memory");
}

// ---------------- kernel 0: f32 -> bf16 tables + bias sums ----------------
__global__ __launch_bounds__(256) void conv_k(
    const float* __restrict__ embed,
    const float* __restrict__ Wih_f, const float* __restrict__ Wih_b,
    const float* __restrict__ Whh_f, const float* __restrict__ Whh_b,
    const float* __restrict__ bih_f, const float* __restrict__ bhh_f,
    const float* __restrict__ bih_b, const float* __restrict__ bhh_b,
    unsigned short* __restrict__ ebf, unsigned short* __restrict__ wix,
    unsigned short* __restrict__ whb, float* __restrict__ bsum)
{
    const int W1 = VOCAB * EE / 4;      // embed float4
    const int W2 = W1 + 2 * 16384;      // wix  (Wih both dirs)
    const int W3 = W2 + 2 * 16384;      // whb  (Whh both dirs)
    const int W4 = W3 + 1024;           // bias sums
    for (int i = blockIdx.x * blockDim.x + threadIdx.x; i < W4;
         i += gridDim.x * blockDim.x) {
        if (i < W1) {
            float4 v = ((const float4*)embed)[i];
            s16x4 s = { f2bf(v.x), f2bf(v.y), f2bf(v.z), f2bf(v.w) };
            ((s16x4*)ebf)[i] = s;
        } else if (i < W2) {
            const int j = i - W1, d = j >> 14, e = j & 16383;
            float4 v = ((const float4*)(d ? Wih_b : Wih_f))[e];
            s16x4 s = { f2bf(v.x), f2bf(v.y), f2bf(v.z), f2bf(v.w) };
            ((s16x4*)wix)[d * 16384 + e] = s;
        } else if (i < W3) {
            const int j = i - W2, d = j >> 14, e = j & 16383;
            float4 v = ((const float4*)(d ? Whh_b : Whh_f))[e];
            s16x4 s = { f2bf(v.x), f2bf(v.y), f2bf(v.z), f2bf(v.w) };
            ((s16x4*)whb)[d * 16384 + e] = s;
        } else {
            const int m = i - W3, d = m >> 9, c = m & 511;
            bsum[d * 512 + c] = d ? (bih_b[c] + bhh_b[c]) : (bih_f[c] + bhh_f[c]);
        }
    }
}

// ---------------- kernel 1: fused BiLSTM (wave-specialized, 2 slots/wave) ----------------
// 256 blocks (128 row-tiles x 2 dirs), 512 thr = 8 waves, launch_bounds(512,2)
// -> 256 VGPRs/wave (weights register-resident; R7's 1024-thr version spilled).
// Waves 0-3: h-recurrence, 2 col-slots each (fh 128 VGPR) + Wout col-tile w.
// Waves 4-7: x-producers, 2 col-slots each (fx 128 VGPR). Embedding fragments
//            are DEPTH-2 REGISTER-PREFETCHED (gather for ts+2 issued at ts;
//            R8 had the ~600-cyc L2/L3 gather latency on the barrier chain
//            every step). lgkm-only barrier; global ops stay in flight.
__global__ __launch_bounds__(512, 2) void lstm_f(
    const int* __restrict__ x, const unsigned short* __restrict__ ebf,
    const unsigned short* __restrict__ wix, const unsigned short* __restrict__ whb,
    const float* __restrict__ bsum,
    const float* __restrict__ h0, const float* __restrict__ c0,
    const float* __restrict__ Wout,
    unsigned short* __restrict__ fpF, unsigned short* __restrict__ fpB)
{
    const int tid = threadIdx.x;
    const int w = tid >> 6, l = tid & 63, qd = l >> 4, n = l & 15;
    const int rt = blockIdx.x & 127, dir = blockIdx.x >> 7;
    const int b0 = rt * 4;
    unsigned short* fp = dir ? fpB : fpF;

    __shared__ short hbuf[2][2048];   // [octet][tile-row 0..15][8]; pads stay 0
    __shared__ short gxb[2][2048];    // [slot 0..7][qd][n][gate 0..3] bf16
    __shared__ int   xsh[4 * 256];    // [j 0..3][t]

    // zero both hbuf buffers + stage x tile
    #pragma unroll
    for (int i = 0; i < 2; ++i) ((s16x4*)hbuf)[tid + i * 512] = (s16x4)0;
    #pragma unroll
    for (int i = 0; i < 2; ++i) {
        const int k = tid + i * 512;
        xsh[k] = x[(size_t)(b0 + (k >> 8)) * SS + (k & 255)];
    }

    if (w < 4) {
        // ---------- h-wave: slots 2w, 2w+1 ----------
        const int s0 = 2 * w, s1 = 2 * w + 1;
        bf16x8 fh0[4][4], fh1[4][4];
        #pragma unroll
        for (int g = 0; g < 4; ++g) {
            #pragma unroll
            for (int kk = 0; kk < 4; ++kk) {
                fh0[g][kk] = *(const bf16x8*)(whb + dir * 65536
                             + (size_t)(g * 128 + 16 * s0 + n) * 128 + kk * 32 + qd * 8);
                fh1[g][kk] = *(const bf16x8*)(whb + dir * 65536
                             + (size_t)(g * 128 + 16 * s1 + n) * 128 + kk * 32 + qd * 8);
            }
        }
        bf16x8 wb[4];
        {
            const int col = w * 16 + n;     // col-tiles 0..3 cover 64 >= LL
            #pragma unroll
            for (int kk = 0; kk < 4; ++kk) {
                bf16x8 v = (bf16x8)0;
                if (col < LL) {
                    const float* p = Wout + (size_t)col * 256 + dir * 128 + kk * 32 + qd * 8;
                    #pragma unroll
                    for (int j = 0; j < 8; ++j) v[j] = f2bf(p[j]);
                }
                wb[kk] = v;
            }
        }
        float cst0 = c0[((size_t)dir * BB + b0 + qd) * HH + 16 * s0 + n];
        float cst1 = c0[((size_t)dir * BB + b0 + qd) * HH + 16 * s1 + n];

        __syncthreads();   // B1: zeros + xsh visible
        {   // h0 -> hbuf[0] tile-rows {0,4,8,12} (512 thr = 4 rows x 128 cols)
            const int j = tid >> 7, c = tid & 127;
            hbuf[0][((c >> 3) * 16 + 4 * j) * 8 + (c & 7)] =
                f2bf(h0[((size_t)dir * BB + b0 + j) * HH + c]);
        }
        __syncthreads();   // B2: hbuf[0] + gxb[0] ready

        const int hid0 = 16 * s0 + n, hc0 = hid0 >> 3, ho0 = hid0 & 7;
        const int hid1 = 16 * s1 + n, hc1 = hid1 >> 3, ho1 = hid1 & 7;
        const int gs0 = (s0 * 64 + qd * 16 + n) * 4;
        const int gs1 = (s1 * 64 + qd * 16 + n) * 4;

        for (int ts = 0; ts < SS; ++ts) {
            const int cur = ts & 1, nxt = cur ^ 1;

            const int2 gi0 = *(const int2*)&gxb[cur][gs0];
            const int2 gi1 = *(const int2*)&gxb[cur][gs1];

            bf16x8 ah[4];
            #pragma unroll
            for (int kk = 0; kk < 4; ++kk)
                ah[kk] = *(const bf16x8*)&hbuf[cur][((kk * 4 + qd) * 16 + n) * 8];

            f32x4 a0[4] = { {0,0,0,0}, {0,0,0,0}, {0,0,0,0}, {0,0,0,0} };
            f32x4 a1[4] = { {0,0,0,0}, {0,0,0,0}, {0,0,0,0}, {0,0,0,0} };
            a0[0][0] = __uint_as_float((unsigned)gi0.x << 16);
            a0[1][0] = __uint_as_float((unsigned)gi0.x & 0xFFFF0000u);
            a0[2][0] = __uint_as_float((unsigned)gi0.y << 16);
            a0[3][0] = __uint_as_float((unsigned)gi0.y & 0xFFFF0000u);
            a1[0][0] = __uint_as_float((unsigned)gi1.x << 16);
            a1[1][0] = __uint_as_float((unsigned)gi1.x & 0xFFFF0000u);
            a1[2][0] = __uint_as_float((unsigned)gi1.y << 16);
            a1[3][0] = __uint_as_float((unsigned)gi1.y & 0xFFFF0000u);

            #pragma unroll
            for (int kk = 0; kk < 4; ++kk) {
                #pragma unroll
                for (int g = 0; g < 4; ++g) {
                    a0[g] = __builtin_amdgcn_mfma_f32_16x16x32_bf16(ah[kk], fh0[g][kk], a0[g], 0, 0, 0);
                    a1[g] = __builtin_amdgcn_mfma_f32_16x16x32_bf16(ah[kk], fh1[g][kk], a1[g], 0, 0, 0);
                }
            }

            if (ts > 0) {   // project h_{ts-1} (reuses ah)
                f32x4 pa = {0, 0, 0, 0};
                #pragma unroll
                for (int kk = 0; kk < 4; ++kk)
                    pa = __builtin_amdgcn_mfma_f32_16x16x32_bf16(ah[kk], wb[kk], pa, 0, 0, 0);
                const int tep = dir ? (SS - ts) : (ts - 1);
                fp[((size_t)(b0 + qd) * SS + tep) * 64 + w * 16 + n]
                    = (unsigned short)f2bf(pa[0]);
            }

            {   // gates (r=0 real), both slots
                const float iv0 = sigf(a0[0][0]), fv0 = sigf(a0[1][0]);
                const float gv0 = tanhf_(a0[2][0]), ov0 = sigf(a0[3][0]);
                const float cc0 = fv0 * cst0 + iv0 * gv0;
                cst0 = cc0;
                hbuf[nxt][(hc0 * 16 + 4 * qd) * 8 + ho0] = f2bf(ov0 * tanhf_(cc0));
                const float iv1 = sigf(a1[0][0]), fv1 = sigf(a1[1][0]);
                const float gv1 = tanhf_(a1[2][0]), ov1 = sigf(a1[3][0]);
                const float cc1 = fv1 * cst1 + iv1 * gv1;
                cst1 = cc1;
                hbuf[nxt][(hc1 * 16 + 4 * qd) * 8 + ho1] = f2bf(ov1 * tanhf_(cc1));
            }
            bar_lds();
        }

        {   // project h_{SS-1} (in hbuf[0], SS even)
            f32x4 pa = {0, 0, 0, 0};
            #pragma unroll
            for (int kk = 0; kk < 4; ++kk) {
                const bf16x8 a = *(const bf16x8*)&hbuf[0][((kk * 4 + qd) * 16 + n) * 8];
                pa = __builtin_amdgcn_mfma_f32_16x16x32_bf16(a, wb[kk], pa, 0, 0, 0);
            }
            const int tep = dir ? 0 : (SS - 1);
            fp[((size_t)(b0 + qd) * SS + tep) * 64 + w * 16 + n]
                = (unsigned short)f2bf(pa[0]);
        }
    } else {
        // ---------- x-wave: slots 2(w-4), 2(w-4)+1, depth-2 reg prefetch ----------
        const int s0 = 2 * (w - 4), s1 = s0 + 1;
        bf16x8 fx0[4][4], fx1[4][4]; float bs0[4], bs1[4];
        #pragma unroll
        for (int g = 0; g < 4; ++g) {
            bs0[g] = bsum[dir * 512 + g * 128 + 16 * s0 + n];
            bs1[g] = bsum[dir * 512 + g * 128 + 16 * s1 + n];
            #pragma unroll
            for (int kk = 0; kk < 4; ++kk) {
                fx0[g][kk] = *(const bf16x8*)(wix + dir * 65536
                             + (size_t)(g * 128 + 16 * s0 + n) * 128 + kk * 32 + qd * 8);
                fx1[g][kk] = *(const bf16x8*)(wix + dir * 65536
                             + (size_t)(g * 128 + 16 * s1 + n) * 128 + kk * 32 + qd * 8);
            }
        }
        const int gs0 = (s0 * 64 + qd * 16 + n) * 4;
        const int gs1 = (s1 * 64 + qd * 16 + n) * 4;
        const int jrow = (n >> 2) * 256;   // A row n -> batch j = n>>2

        auto loadfrag = [&](int t, bf16x8* e) {   // e <- emb frags for gx(t)
            const int te = dir ? (SS - 1 - t) : t;
            const int xi = xsh[jrow + te];
            const unsigned short* er = ebf + (size_t)xi * EE + qd * 8;
            e[0] = *(const bf16x8*)(er);
            e[1] = *(const bf16x8*)(er + 32);
            e[2] = *(const bf16x8*)(er + 64);
            e[3] = *(const bf16x8*)(er + 96);
        };
        auto compute = [&](const bf16x8* e, int buf) {   // gxb[buf] <- gx
            f32x4 c0a[4] = { {0,0,0,0}, {0,0,0,0}, {0,0,0,0}, {0,0,0,0} };
            f32x4 c1a[4] = { {0,0,0,0}, {0,0,0,0}, {0,0,0,0}, {0,0,0,0} };
            #pragma unroll
            for (int g = 0; g < 4; ++g) {
                #pragma unroll
                for (int kk = 0; kk < 4; ++kk) {
                    c0a[g] = __builtin_amdgcn_mfma_f32_16x16x32_bf16(e[kk], fx0[g][kk], c0a[g], 0, 0, 0);
                    c1a[g] = __builtin_amdgcn_mfma_f32_16x16x32_bf16(e[kk], fx1[g][kk], c1a[g], 0, 0, 0);
                }
            }
            s16x4 p0 = { f2bf(c0a[0][0] + bs0[0]), f2bf(c0a[1][0] + bs0[1]),
                         f2bf(c0a[2][0] + bs0[2]), f2bf(c0a[3][0] + bs0[3]) };
            s16x4 p1 = { f2bf(c1a[0][0] + bs1[0]), f2bf(c1a[1][0] + bs1[1]),
                         f2bf(c1a[2][0] + bs1[2]), f2bf(c1a[3][0] + bs1[3]) };
            *(s16x4*)&gxb[buf][gs0] = p0;
            *(s16x4*)&gxb[buf][gs1] = p1;
        };

        __syncthreads();   // B1: xsh visible
        bf16x8 eT[4], eP[4], eQ[4];
        loadfrag(0, eT);
        compute(eT, 0);          // gxb[0] = gx(0)  (one-time stall, pre-loop)
        loadfrag(1, eP);         // frags for gx(1), produced at ts=0
        __syncthreads();   // B2

        // 2-step unrolled: at ts, issue gather for gx(ts+2), produce gx(ts+1)
        auto xstep = [&](int ts, bf16x8* use, bf16x8* pre) {
            if (ts + 2 < SS) loadfrag(ts + 2, pre);
            if (ts + 1 < SS) compute(use, (ts & 1) ^ 1);
            bar_lds();
        };
        for (int ts = 0; ts < SS; ts += 2) {
            xstep(ts,     eP, eQ);
            xstep(ts + 1, eQ, eP);
        }
    }
}

// ---------------- kernel 2: CRF forward + gold + reduce ----------------
// One wave per batch element, 512 blocks x 64 thr; launch_bounds(64,1) lifts
// the VGPR cap so etr[59] stays register-resident.
__global__ __launch_bounds__(64, 1) void crf_k(
    const unsigned short* __restrict__ fpF, const unsigned short* __restrict__ fpB,
    const float* __restrict__ bout, const int* __restrict__ y,
    const float* __restrict__ trans, float* __restrict__ out)
{
    const int j = threadIdx.x;
    const int b = blockIdx.x;
    const size_t bS = (size_t)b * SS;
    const bool valid = (j < LL);
    const int  jr = valid ? j : (LL - 1);

    float etr[LL];
    #pragma unroll
    for (int i = 0; i < LL; ++i) {
        const float t = trans[jr * LL + i];
        etr[i] = valid ? __builtin_amdgcn_exp2f(t * 1.44269504f) : 0.0f;
    }
    const float bo = valid ? bout[jr] : 0.0f;

    float alpha = valid ? ((j == STARTL) ? 0.0f : -10000.0f) : -1e30f;

    float fF[8], fB[8];
    #pragma unroll
    for (int q = 0; q < 8; ++q) {
        fF[q] = bf2f(fpF[(bS + q) * 64 + j]);
        fB[q] = bf2f(fpB[(bS + q) * 64 + j]);
    }

    for (int t0 = 0; t0 < SS; t0 += 8) {
        float nF[8], nB[8];
        #pragma unroll
        for (int q = 0; q < 8; ++q) { nF[q] = 0.0f; nB[q] = 0.0f; }
        if (t0 + 8 < SS) {
            #pragma unroll
            for (int q = 0; q < 8; ++q) {
                nF[q] = bf2f(fpF[(bS + t0 + 8 + q) * 64 + j]);
                nB[q] = bf2f(fpB[(bS + t0 + 8 + q) * 64 + j]);
            }
        }
        #pragma unroll
        for (int u = 0; u < 8; ++u) {
            const float K = fmaxf(
                __uint_as_float(__builtin_amdgcn_readlane(__float_as_uint(alpha), 1)),
                __uint_as_float(__builtin_amdgcn_readlane(__float_as_uint(alpha), STARTL)));
            const float ea = __builtin_amdgcn_exp2f((alpha - K) * 1.44269504f);
            float d0 = 0.0f, d1 = 0.0f, d2 = 0.0f, d3 = 0.0f;
            #pragma unroll
            for (int i = 0; i < LL; i += 4) {
                d0 += etr[i] * __uint_as_float(__builtin_amdgcn_readlane(__float_as_uint(ea), i));
                if (i + 1 < LL) d1 += etr[i+1] * __uint_as_float(__builtin_amdgcn_readlane(__float_as_uint(ea), i+1));
                if (i + 2 < LL) d2 += etr[i+2] * __uint_as_float(__builtin_amdgcn_readlane(__float_as_uint(ea), i+2));
                if (i + 3 < LL) d3 += etr[i+3] * __uint_as_float(__builtin_amdgcn_readlane(__float_as_uint(ea), i+3));
            }
            const float dot = (d0 + d1) + (d2 + d3);
            alpha = (fF[u] + fB[u] + bo) + K + 0.69314718f * __builtin_amdgcn_logf(dot);
        }
        #pragma unroll
        for (int q = 0; q < 8; ++q) { fF[q] = nF[q]; fB[q] = nB[q]; }
    }

    const float v  = alpha + trans[STOPL * LL + jr];
    const float m2 = wmax64(v);
    const float s  = wsum64(__builtin_amdgcn_exp2f((v - m2) * 1.44269504f));
    const float fwd = m2 + 0.69314718f * __builtin_amdgcn_logf(s);

    float g = 0.0f;
    #pragma unroll
    for (int q = 0; q < 4; ++q) {
        const int t  = q * 64 + j;
        const int yt = y[bS + t];
        const int yp = t ? y[bS + t - 1] : STARTL;
        g += bf2f(fpF[(bS + t) * 64 + yt]) + bf2f(fpB[(bS + t) * 64 + yt])
           + bout[yt] + trans[yt * LL + yp];
    }
    g = wsum64(g);

    if (j == 0) {
        g += trans[STOPL * LL + y[bS + SS - 1]];
        atomicAdd(out, fwd - g);
    }
}

// ---------------- launcher ----------------
extern "C" void kernel_launch(void* const* d_in, const int* in_sizes, int n_in,
                              void* d_out, int out_size, void* d_ws, size_t ws_size,
                              hipStream_t stream)
{
    (void)in_sizes; (void)n_in; (void)out_size; (void)ws_size;
    const int*   x      = (const int*)  d_in[0];
    const int*   y      = (const int*)  d_in[1];
    const float* embed  = (const float*)d_in[2];
    const float* Wih_f  = (const float*)d_in[3];
    const float* Whh_f  = (const float*)d_in[4];
    const float* bih_f  = (const float*)d_in[5];
    const float* bhh_f  = (const float*)d_in[6];
    const float* Wih_b  = (const float*)d_in[7];
    const float* Whh_b  = (const float*)d_in[8];
    const float* bih_b  = (const float*)d_in[9];
    const float* bhh_b  = (const float*)d_in[10];
    const float* Wout   = (const float*)d_in[11];
    const float* bout   = (const float*)d_in[12];
    const float* trans  = (const float*)d_in[13];
    const float* h0     = (const float*)d_in[14];
    const float* c0     = (const float*)d_in[15];

    const size_t MiB = 1ull << 20;
    unsigned short* fpF  = (unsigned short*)d_ws;                                   // 16 MiB
    unsigned short* fpB  = (unsigned short*)((char*)d_ws + 16 * MiB);               // 16 MiB
    unsigned short* ebf  = (unsigned short*)((char*)d_ws + 32 * MiB);               // 12.8 MB
    unsigned short* wix  = (unsigned short*)((char*)d_ws + 45 * MiB);               // 256 KiB
    unsigned short* whb  = (unsigned short*)((char*)d_ws + 45 * MiB + 256 * 1024);  // 256 KiB
    float*          bsum = (float*)((char*)d_ws + 45 * MiB + 512 * 1024);           // 4 KiB

    hipMemsetAsync(d_out, 0, sizeof(float), stream);
    conv_k<<<2048, 256, 0, stream>>>(embed, Wih_f, Wih_b, Whh_f, Whh_b,
                                     bih_f, bhh_f, bih_b, bhh_b,
                                     ebf, wix, whb, bsum);
    lstm_f<<<256, 512, 0, stream>>>(x, ebf, wix, whb, bsum, h0, c0, Wout,
                                    fpF, fpB);
    crf_k<<<BB, 64, 0, stream>>>(fpF, fpB, bout, y, trans, (float*)d_out);
}